// Round 10
// baseline (179.605 us; speedup 1.0000x reference)
//
#include <hip/hip_runtime.h>
#include <hip/hip_bf16.h>

constexpr int B = 2, S = 2048, D = 1024;
constexpr int H = 16, KVH = 4, HD = 64;
constexpr int BS = B * S;                 // 4096
constexpr int QS = 1536;                  // fused qkv width

typedef __attribute__((ext_vector_type(8))) short short8;
typedef __attribute__((ext_vector_type(4))) float floatx4;

#define GPTR(p) ((__attribute__((address_space(1))) void*)(p))
#define LPTR(p) ((__attribute__((address_space(3))) void*)(p))

static __device__ __forceinline__ unsigned short f2bf(float f) {
  union { float f; unsigned u; } c{f};
  unsigned r = (c.u + 0x7FFFu + ((c.u >> 16) & 1u)) >> 16;
  return (unsigned short)r;
}
static __device__ __forceinline__ short8 pack8(float4 a, float4 b) {
  short8 r;
  r[0] = (short)f2bf(a.x); r[1] = (short)f2bf(a.y);
  r[2] = (short)f2bf(a.z); r[3] = (short)f2bf(a.w);
  r[4] = (short)f2bf(b.x); r[5] = (short)f2bf(b.y);
  r[6] = (short)f2bf(b.z); r[7] = (short)f2bf(b.w);
  return r;
}

// ---------------------------------------------------------------------------
// Fused QKV GEMM + RoPE + V-transpose, reading RAW fp32 x and weights.
// C[4096,1536] = x[4096,1024] * Wqkv[1024,1536], never materialized.
// 128x64 tile, BK=64 (two 32-k sections in m97 [row][32] LDS layout), 16 iters.
// A staged via VGPR cvt (dense lane-contiguous ds_write: byte off = tid*16,
// conflict-free). B staged via 4x4 in-register micro-transpose (w is [K][N]
// row-major; Bs wants [n][k]).
// Grid (rows=32, cols=24): blockIdx.x fast -> A row-tiles partition across
// XCDs for L2 residency.
// ---------------------------------------------------------------------------
__global__ __launch_bounds__(256) void gemm_qkv_kernel(
    const float* __restrict__ x,
    const float* __restrict__ wq, const float* __restrict__ wk,
    const float* __restrict__ wv,
    const float* __restrict__ cs, const float* __restrict__ sn,
    unsigned short* __restrict__ qb, unsigned short* __restrict__ kb,
    unsigned short* __restrict__ vt) {
  __shared__ unsigned short As[2 * 128 * 32];   // 16 KB
  __shared__ unsigned short Bs[2 * 64 * 32];    // 8 KB
  const int tid = threadIdx.x;
  const int lane = tid & 63, wvid = tid >> 6;
  const int wy = wvid >> 1, wx = wvid & 1;
  const int quad = lane >> 4, lrow = lane & 15;
  const size_t row0 = (size_t)blockIdx.x * 128;
  const size_t col0 = (size_t)blockIdx.y * 64;

  // block-uniform weight region select (64-col tile never straddles)
  const float* wsrc; int Nw, cb;
  if (col0 < 1024)      { wsrc = wq; Nw = 1024; cb = (int)col0; }
  else if (col0 < 1280) { wsrc = wk; Nw = 256;  cb = (int)col0 - 1024; }
  else                  { wsrc = wv; Nw = 256;  cb = (int)col0 - 1280; }

  floatx4 acc[4][2];
#pragma unroll
  for (int i = 0; i < 4; ++i)
#pragma unroll
    for (int j = 0; j < 2; ++j) acc[i][j] = floatx4{0.f, 0.f, 0.f, 0.f};

  // A staging: thread -> (row = tid>>2 in 0..63, 8-elem k-chunk = (tid&3)*8)
  const int ar = tid >> 2;
  const int akc = (tid & 3) * 8;
  const float* gxa = x + (row0 + ar) * 1024 + akc;        // rows 0..63
  const float* gxb = x + (row0 + 64 + ar) * 1024 + akc;   // rows 64..127
  const int aoff = ar * 32 + akc;                          // ushort idx = tid*8

  // B staging: thread -> section s=tid>>7, 4x4 micro-tile (n=ng*4, k=kg*4)
  const int bsec = tid >> 7;
  const int bu = tid & 127;
  const int bn = (bu & 15) * 4;
  const int bk = (bu >> 4) * 4;
  const float* gw = wsrc + (size_t)(bsec * 32 + bk) * Nw + cb + bn;

  for (int k0 = 0; k0 < 1024; k0 += 64) {
    // global loads (overlap with previous iteration's MFMAs)
    float4 al0 = *(const float4*)(gxa + k0);
    float4 al1 = *(const float4*)(gxa + k0 + 4);
    float4 al2 = *(const float4*)(gxa + k0 + 32);
    float4 al3 = *(const float4*)(gxa + k0 + 36);
    float4 ah0 = *(const float4*)(gxb + k0);
    float4 ah1 = *(const float4*)(gxb + k0 + 4);
    float4 ah2 = *(const float4*)(gxb + k0 + 32);
    float4 ah3 = *(const float4*)(gxb + k0 + 36);
    const float* gwk = gw + (size_t)k0 * Nw;
    float4 b0 = *(const float4*)(gwk);
    float4 b1 = *(const float4*)(gwk + Nw);
    float4 b2 = *(const float4*)(gwk + 2 * Nw);
    float4 b3 = *(const float4*)(gwk + 3 * Nw);

    __syncthreads();
    // A: dense lane-contiguous b128 writes (conflict-free)
    *(short8*)&As[aoff]               = pack8(al0, al1);   // s0 rows 0..63
    *(short8*)&As[2048 + aoff]        = pack8(ah0, ah1);   // s0 rows 64..127
    *(short8*)&As[4096 + aoff]        = pack8(al2, al3);   // s1 rows 0..63
    *(short8*)&As[4096 + 2048 + aoff] = pack8(ah2, ah3);   // s1 rows 64..127
    // B: 4x4 register transpose -> [n][k]
#pragma unroll
    for (int dn = 0; dn < 4; ++dn) {
      const float* c0 = (const float*)&b0;
      const float* c1 = (const float*)&b1;
      const float* c2 = (const float*)&b2;
      const float* c3 = (const float*)&b3;
      uint2 o;
      o.x = (unsigned)f2bf(c0[dn]) | ((unsigned)f2bf(c1[dn]) << 16);
      o.y = (unsigned)f2bf(c2[dn]) | ((unsigned)f2bf(c3[dn]) << 16);
      *(uint2*)&Bs[bsec * 2048 + (bn + dn) * 32 + bk] = o;
    }
    __syncthreads();

#pragma unroll
    for (int s = 0; s < 2; ++s) {
      short8 af[4], bg[2];
#pragma unroll
      for (int mi = 0; mi < 4; ++mi)
        af[mi] = *(const short8*)&As[s * 4096 + (wy * 64 + mi * 16 + lrow) * 32 + quad * 8];
#pragma unroll
      for (int ni = 0; ni < 2; ++ni)
        bg[ni] = *(const short8*)&Bs[s * 2048 + (wx * 32 + ni * 16 + lrow) * 32 + quad * 8];
#pragma unroll
      for (int mi = 0; mi < 4; ++mi)
#pragma unroll
        for (int ni = 0; ni < 2; ++ni)
          acc[mi][ni] = __builtin_amdgcn_mfma_f32_16x16x32_bf16(af[mi], bg[ni], acc[mi][ni], 0, 0, 0);
    }
  }

  // ---- fused epilogue: RoPE (q/k) or transposed V store ----
  const int col_wave = (int)col0 + wx * 32;     // wave-uniform, within one head
  const int h = col_wave >> 6;
  const int hc = col_wave & 63;
  const int sb = (int)(row0 & 2047) + wy * 64;
  const int bidx = (int)(row0 >> 11);

  if (h < 20) {
    unsigned short* dst = (h < 16) ? qb : kb;
    const int dstride = (h < 16) ? 1024 : 256;
    const int dcol = (h < 16) ? col_wave : (col_wave - 1024);
    const bool ev = (lrow & 1) == 0;
#pragma unroll
    for (int mi = 0; mi < 4; ++mi) {
#pragma unroll
      for (int ni = 0; ni < 2; ++ni) {
        int ff = (hc + ni * 16 + lrow) >> 1;
#pragma unroll
        for (int r = 0; r < 4; ++r) {
          int s = sb + mi * 16 + quad * 4 + r;
          float v = acc[mi][ni][r];
          float p = __shfl_xor(v, 1);
          float c = cs[s * 32 + ff];
          float si = sn[s * 32 + ff];
          float o = ev ? (v * c - p * si) : (v * c + p * si);
          size_t row = row0 + wy * 64 + mi * 16 + quad * 4 + r;
          dst[row * dstride + dcol + ni * 16 + lrow] = f2bf(o);
        }
      }
    }
  } else {
    const int kvh = h - 20;
    const int g = bidx * KVH + kvh;
#pragma unroll
    for (int mi = 0; mi < 4; ++mi) {
#pragma unroll
      for (int ni = 0; ni < 2; ++ni) {
        int d = hc + ni * 16 + lrow;
        int s0 = sb + mi * 16 + quad * 4;
        ushort4 o;
        o.x = f2bf(acc[mi][ni][0]); o.y = f2bf(acc[mi][ni][1]);
        o.z = f2bf(acc[mi][ni][2]); o.w = f2bf(acc[mi][ni][3]);
        *(ushort4*)&vt[((size_t)(g * 64 + d)) * S + s0] = o;
      }
    }
  }
}

// ---------------------------------------------------------------------------
// Output projection: out[4096,1024] fp32 = ao[4096,1024] bf16 * wo[1024,1024].
// A via async global_load_lds (bf16 already); B = raw fp32 wo micro-transposed.
// ---------------------------------------------------------------------------
__global__ __launch_bounds__(256) void gemm_bt_kernel(
    const unsigned short* __restrict__ ao, const float* __restrict__ wo,
    float* __restrict__ out) {
  __shared__ unsigned short As[2 * 128 * 32];
  __shared__ unsigned short Bs[2 * 64 * 32];
  const int tid = threadIdx.x;
  const int lane = tid & 63, wvid = tid >> 6;
  const int wy = wvid >> 1, wx = wvid & 1;
  const int quad = lane >> 4, lrow = lane & 15;
  const size_t row0 = (size_t)blockIdx.x * 128;
  const size_t col0 = (size_t)blockIdx.y * 64;

  floatx4 acc[4][2];
#pragma unroll
  for (int i = 0; i < 4; ++i)
#pragma unroll
    for (int j = 0; j < 2; ++j) acc[i][j] = floatx4{0.f, 0.f, 0.f, 0.f};

  // A async staging (m97 pattern): wave covers 32 rows per section-half
  const int srow = wvid * 32 + (lane >> 2);
  const int schk = (lane & 3) * 8;
  const unsigned short* gA = ao + (row0 + srow) * 1024 + schk;
  char* ldsA = (char*)As + wvid * 2048;

  // B staging
  const int bsec = tid >> 7;
  const int bu = tid & 127;
  const int bn = (bu & 15) * 4;
  const int bk = (bu >> 4) * 4;
  const float* gw = wo + (size_t)(bsec * 32 + bk) * 1024 + col0 + bn;

  for (int k0 = 0; k0 < 1024; k0 += 64) {
    const float* gwk = gw + (size_t)k0 * 1024;
    float4 b0 = *(const float4*)(gwk);
    float4 b1 = *(const float4*)(gwk + 1024);
    float4 b2 = *(const float4*)(gwk + 2048);
    float4 b3 = *(const float4*)(gwk + 3072);

    __syncthreads();
#pragma unroll
    for (int s = 0; s < 2; ++s) {
      __builtin_amdgcn_global_load_lds(GPTR(gA + k0 + s * 32),
                                       LPTR(ldsA + s * 8192), 16, 0, 0);
      __builtin_amdgcn_global_load_lds(GPTR(gA + 16 * 1024 + k0 + s * 32),
                                       LPTR(ldsA + s * 8192 + 1024), 16, 0, 0);
    }
#pragma unroll
    for (int dn = 0; dn < 4; ++dn) {
      const float* c0 = (const float*)&b0;
      const float* c1 = (const float*)&b1;
      const float* c2 = (const float*)&b2;
      const float* c3 = (const float*)&b3;
      uint2 o;
      o.x = (unsigned)f2bf(c0[dn]) | ((unsigned)f2bf(c1[dn]) << 16);
      o.y = (unsigned)f2bf(c2[dn]) | ((unsigned)f2bf(c3[dn]) << 16);
      *(uint2*)&Bs[bsec * 2048 + (bn + dn) * 32 + bk] = o;
    }
    __syncthreads();

#pragma unroll
    for (int s = 0; s < 2; ++s) {
      short8 af[4], bg[2];
#pragma unroll
      for (int mi = 0; mi < 4; ++mi)
        af[mi] = *(const short8*)&As[s * 4096 + (wy * 64 + mi * 16 + lrow) * 32 + quad * 8];
#pragma unroll
      for (int ni = 0; ni < 2; ++ni)
        bg[ni] = *(const short8*)&Bs[s * 2048 + (wx * 32 + ni * 16 + lrow) * 32 + quad * 8];
#pragma unroll
      for (int mi = 0; mi < 4; ++mi)
#pragma unroll
        for (int ni = 0; ni < 2; ++ni)
          acc[mi][ni] = __builtin_amdgcn_mfma_f32_16x16x32_bf16(af[mi], bg[ni], acc[mi][ni], 0, 0, 0);
    }
  }

#pragma unroll
  for (int mi = 0; mi < 4; ++mi)
#pragma unroll
    for (int ni = 0; ni < 2; ++ni) {
      size_t col = col0 + wx * 32 + ni * 16 + lrow;
      size_t rowb = row0 + wy * 64 + mi * 16 + quad * 4;
#pragma unroll
      for (int r = 0; r < 4; ++r)
        out[(rowb + r) * 1024 + col] = acc[mi][ni][r];
    }
}

// ---------------------------------------------------------------------------
// MFMA flash attention. One wave per (b, h, 16-query block). (unchanged)
// ---------------------------------------------------------------------------
__global__ __launch_bounds__(256) void attn_kernel(
    const unsigned short* __restrict__ qb,   // [BS][1024]
    const unsigned short* __restrict__ kb,   // [BS][256]
    const unsigned short* __restrict__ vt,   // [B*KVH][64][S]
    unsigned short* __restrict__ ao) {       // [BS][1024]
  __shared__ __align__(16) unsigned short plds[4][16][104];
  const int w = threadIdx.x >> 6, lane = threadIdx.x & 63;
  const int lrow = lane & 15, quad = lane >> 4;
  const int wg = blockIdx.x * 4 + w;
  const int h = wg & (H - 1);
  const int qblk = wg >> 4;
  const int i0 = (qblk & (S / 16 - 1)) * 16;
  const int b = qblk >> 7;
  const int kvh = h >> 2;
  const int jbase = i0 - 80;

  const unsigned short* qrow = qb + (size_t)(b * S + i0 + lrow) * 1024 + h * 64 + quad * 8;
  short8 qf0 = *(const short8*)qrow;
  short8 qf1 = *(const short8*)(qrow + 32);

  floatx4 sc[6];
#pragma unroll
  for (int t = 0; t < 6; ++t) {
    int j = jbase + t * 16 + lrow;
    int jc = j < 0 ? 0 : j;
    const unsigned short* krow = kb + (size_t)(b * S + jc) * 256 + kvh * 64 + quad * 8;
    short8 kf0 = *(const short8*)krow;
    short8 kf1 = *(const short8*)(krow + 32);
    floatx4 a = {0.f, 0.f, 0.f, 0.f};
    a = __builtin_amdgcn_mfma_f32_16x16x32_bf16(qf0, kf0, a, 0, 0, 0);
    a = __builtin_amdgcn_mfma_f32_16x16x32_bf16(qf1, kf1, a, 0, 0, 0);
    sc[t] = a;
  }

  float sv[6][4];
  float mx[4] = {-1e30f, -1e30f, -1e30f, -1e30f};
#pragma unroll
  for (int t = 0; t < 6; ++t) {
    int j = jbase + t * 16 + lrow;
#pragma unroll
    for (int r = 0; r < 4; ++r) {
      int dji = (i0 + quad * 4 + r) - j;
      bool valid = (j >= 0) && (dji >= 0) && (dji <= 64);
      float s = valid ? sc[t][r] * 0.125f : -1e30f;
      sv[t][r] = s;
      mx[r] = fmaxf(mx[r], s);
    }
  }
#pragma unroll
  for (int r = 0; r < 4; ++r)
#pragma unroll
    for (int off = 8; off > 0; off >>= 1)
      mx[r] = fmaxf(mx[r], __shfl_xor(mx[r], off));

  float ls[4] = {0.f, 0.f, 0.f, 0.f};
#pragma unroll
  for (int t = 0; t < 6; ++t)
#pragma unroll
    for (int r = 0; r < 4; ++r) {
      float e = __expf(sv[t][r] - mx[r]);
      sv[t][r] = e;
      ls[r] += e;
    }
#pragma unroll
  for (int r = 0; r < 4; ++r) {
#pragma unroll
    for (int off = 8; off > 0; off >>= 1)
      ls[r] += __shfl_xor(ls[r], off);
    ls[r] = 1.f / ls[r];
  }
#pragma unroll
  for (int t = 0; t < 6; ++t)
#pragma unroll
    for (int r = 0; r < 4; ++r)
      plds[w][quad * 4 + r][t * 16 + lrow] = f2bf(sv[t][r] * ls[r]);
  __syncthreads();

  floatx4 oc[4];
#pragma unroll
  for (int mt = 0; mt < 4; ++mt) oc[mt] = floatx4{0.f, 0.f, 0.f, 0.f};
  const unsigned short* vbase = vt + (size_t)(b * KVH + kvh) * 64 * S;
#pragma unroll
  for (int c = 0; c < 3; ++c) {
    short8 pf = *(const short8*)&plds[w][lrow][c * 32 + quad * 8];
    int j = jbase + c * 32 + quad * 8;
    int jc = j < 0 ? 0 : j;
#pragma unroll
    for (int mt = 0; mt < 4; ++mt) {
      short8 vf = *(const short8*)(vbase + (size_t)(mt * 16 + lrow) * S + jc);
      oc[mt] = __builtin_amdgcn_mfma_f32_16x16x32_bf16(vf, pf, oc[mt], 0, 0, 0);
    }
  }

#pragma unroll
  for (int mt = 0; mt < 4; ++mt) {
    ushort4 o;
    o.x = f2bf(oc[mt][0]); o.y = f2bf(oc[mt][1]);
    o.z = f2bf(oc[mt][2]); o.w = f2bf(oc[mt][3]);
    *(ushort4*)(ao + (size_t)(b * S + i0 + lrow) * 1024 + h * 64 + mt * 16 + quad * 4) = o;
  }
}

// ---------------------------------------------------------------------------
extern "C" void kernel_launch(void* const* d_in, const int* in_sizes, int n_in,
                              void* d_out, int out_size, void* d_ws, size_t ws_size,
                              hipStream_t stream) {
  const float* x  = (const float*)d_in[0];
  const float* fc = (const float*)d_in[1];
  const float* fs = (const float*)d_in[2];
  const float* wq = (const float*)d_in[3];
  const float* wk = (const float*)d_in[4];
  const float* wv = (const float*)d_in[5];
  const float* wo = (const float*)d_in[6];
  float* out = (float*)d_out;

  // ws: [qb 8M][kb 2M][vT 2M][ao 8M] = 20 MiB
  char* base = (char*)d_ws;
  unsigned short* qb = (unsigned short*)base;
  unsigned short* kb = (unsigned short*)(base + (8u << 20));
  unsigned short* vT = (unsigned short*)(base + (10u << 20));
  unsigned short* ao = (unsigned short*)(base + (12u << 20));

  // 1) fused QKV GEMM (raw fp32 inputs) + RoPE + V-transpose
  gemm_qkv_kernel<<<dim3(BS / 128, QS / 64), 256, 0, stream>>>(
      x, wq, wk, wv, fc, fs, qb, kb, vT);

  // 2) MFMA attention -> ao bf16 [4096,1024]
  attn_kernel<<<(BS / 16) * H / 4, 256, 0, stream>>>(qb, kb, vT, ao);

  // 3) output projection (raw fp32 wo) -> fp32
  gemm_bt_kernel<<<dim3(BS / 128, D / 64), 256, 0, stream>>>(ao, wo, out);
}

// Round 11
// 165.472 us; speedup vs baseline: 1.0854x; 1.0854x over previous
//
#include <hip/hip_runtime.h>
#include <hip/hip_bf16.h>

constexpr int B = 2, S = 2048, D = 1024;
constexpr int H = 16, KVH = 4, HD = 64;
constexpr int BS = B * S;                 // 4096
constexpr int QS = 1536;                  // fused qkv width

typedef __attribute__((ext_vector_type(8))) short short8;
typedef __attribute__((ext_vector_type(4))) float floatx4;

static __device__ __forceinline__ unsigned short f2bf(float f) {
  union { float f; unsigned u; } c{f};
  unsigned r = (c.u + 0x7FFFu + ((c.u >> 16) & 1u)) >> 16;
  return (unsigned short)r;
}
static __device__ __forceinline__ short8 pack8(float4 a, float4 b) {
  short8 r;
  r[0] = (short)f2bf(a.x); r[1] = (short)f2bf(a.y);
  r[2] = (short)f2bf(a.z); r[3] = (short)f2bf(a.w);
  r[4] = (short)f2bf(b.x); r[5] = (short)f2bf(b.y);
  r[6] = (short)f2bf(b.z); r[7] = (short)f2bf(b.w);
  return r;
}

// ---------------------------------------------------------------------------
// LDS tile layout (both GEMMs): [sec][row][32 ushorts], XOR-swizzled at 16B
// granularity: 16B-chunk c of row r is stored at chunk (c ^ ((r>>2)&3)).
//  - frag reads (16 lanes, consecutive rows): 2-way banked = free
//  - A staging writes (lane-contiguous 16B): <=2-way
//  - B micro-transpose uint2 writes: 4-way (was 16-way) on a small fraction
// ---------------------------------------------------------------------------

// ---------------------------------------------------------------------------
// Fused QKV GEMM + RoPE + V-transpose, reading RAW fp32 x and weights.
// 128x64 tile, BK=64 (two 32-k sections), grid (rows=32, cols=24) XCD-aware.
// ---------------------------------------------------------------------------
__global__ __launch_bounds__(256) void gemm_qkv_kernel(
    const float* __restrict__ x,
    const float* __restrict__ wq, const float* __restrict__ wk,
    const float* __restrict__ wv,
    const float* __restrict__ cs, const float* __restrict__ sn,
    unsigned short* __restrict__ qb, unsigned short* __restrict__ kb,
    unsigned short* __restrict__ vt) {
  __shared__ unsigned short As[2 * 128 * 32];   // 16 KB
  __shared__ unsigned short Bs[2 * 64 * 32];    // 8 KB
  const int tid = threadIdx.x;
  const int lane = tid & 63, wvid = tid >> 6;
  const int wy = wvid >> 1, wx = wvid & 1;
  const int quad = lane >> 4, lrow = lane & 15;
  const size_t row0 = (size_t)blockIdx.x * 128;
  const size_t col0 = (size_t)blockIdx.y * 64;

  // block-uniform weight region select (64-col tile never straddles)
  const float* wsrc; int Nw, cb;
  if (col0 < 1024)      { wsrc = wq; Nw = 1024; cb = (int)col0; }
  else if (col0 < 1280) { wsrc = wk; Nw = 256;  cb = (int)col0 - 1024; }
  else                  { wsrc = wv; Nw = 256;  cb = (int)col0 - 1280; }

  floatx4 acc[4][2];
#pragma unroll
  for (int i = 0; i < 4; ++i)
#pragma unroll
    for (int j = 0; j < 2; ++j) acc[i][j] = floatx4{0.f, 0.f, 0.f, 0.f};

  // A staging: thread -> (row ar in 0..63, chunk ac in 0..3); swizzled write
  const int ar = tid >> 2;
  const int ac = tid & 3;
  const int aswz = ((ac ^ ((ar >> 2) & 3)) * 8);
  const int aoffL = ar * 32 + aswz;
  const int aoffH = (ar + 64) * 32 + aswz;
  const float* gxa = x + (row0 + ar) * 1024 + ac * 8;
  const float* gxb = x + (row0 + 64 + ar) * 1024 + ac * 8;

  // B staging: thread -> section bsec, 4x4 micro-tile (n = bn..bn+3, k = bkq..+3)
  const int bsec = tid >> 7;
  const int bu = tid & 127;
  const int bn = (bu & 15) * 4;
  const int bkq = (bu >> 4) * 4;
  const int bchunk = bkq >> 3, bslot = (bkq >> 2) & 1;
  const float* gw = wsrc + (size_t)(bsec * 32 + bkq) * Nw + cb + bn;

  // frag-read swizzle (key = lrow>>2 for both A and B rows)
  const int fswz = (quad ^ (lrow >> 2)) * 8;

  for (int k0 = 0; k0 < 1024; k0 += 64) {
    float4 a0l0 = *(const float4*)(gxa + k0);
    float4 a0l1 = *(const float4*)(gxa + k0 + 4);
    float4 a0h0 = *(const float4*)(gxb + k0);
    float4 a0h1 = *(const float4*)(gxb + k0 + 4);
    float4 a1l0 = *(const float4*)(gxa + k0 + 32);
    float4 a1l1 = *(const float4*)(gxa + k0 + 36);
    float4 a1h0 = *(const float4*)(gxb + k0 + 32);
    float4 a1h1 = *(const float4*)(gxb + k0 + 36);
    const float* gwk = gw + (size_t)k0 * Nw;
    float4 b0 = *(const float4*)(gwk);
    float4 b1 = *(const float4*)(gwk + Nw);
    float4 b2 = *(const float4*)(gwk + 2 * Nw);
    float4 b3 = *(const float4*)(gwk + 3 * Nw);

    __syncthreads();
    *(short8*)&As[aoffL]        = pack8(a0l0, a0l1);
    *(short8*)&As[aoffH]        = pack8(a0h0, a0h1);
    *(short8*)&As[4096 + aoffL] = pack8(a1l0, a1l1);
    *(short8*)&As[4096 + aoffH] = pack8(a1h0, a1h1);
#pragma unroll
    for (int dn = 0; dn < 4; ++dn) {
      const float* c0 = (const float*)&b0;
      const float* c1 = (const float*)&b1;
      const float* c2 = (const float*)&b2;
      const float* c3 = (const float*)&b3;
      int n = bn + dn;
      int key = (n >> 2) & 3;
      uint2 o;
      o.x = (unsigned)f2bf(c0[dn]) | ((unsigned)f2bf(c1[dn]) << 16);
      o.y = (unsigned)f2bf(c2[dn]) | ((unsigned)f2bf(c3[dn]) << 16);
      *(uint2*)&Bs[bsec * 2048 + n * 32 + ((bchunk ^ key) * 8) + bslot * 4] = o;
    }
    __syncthreads();

#pragma unroll
    for (int s = 0; s < 2; ++s) {
      short8 af[4], bg[2];
#pragma unroll
      for (int mi = 0; mi < 4; ++mi)
        af[mi] = *(const short8*)&As[s * 4096 + (wy * 64 + mi * 16 + lrow) * 32 + fswz];
#pragma unroll
      for (int ni = 0; ni < 2; ++ni)
        bg[ni] = *(const short8*)&Bs[s * 2048 + (wx * 32 + ni * 16 + lrow) * 32 + fswz];
#pragma unroll
      for (int mi = 0; mi < 4; ++mi)
#pragma unroll
        for (int ni = 0; ni < 2; ++ni)
          acc[mi][ni] = __builtin_amdgcn_mfma_f32_16x16x32_bf16(af[mi], bg[ni], acc[mi][ni], 0, 0, 0);
    }
  }

  // ---- fused epilogue: RoPE (q/k) or transposed V store ----
  const int col_wave = (int)col0 + wx * 32;     // wave-uniform, within one head
  const int h = col_wave >> 6;
  const int hc = col_wave & 63;
  const int sb = (int)(row0 & 2047) + wy * 64;
  const int bidx = (int)(row0 >> 11);

  if (h < 20) {
    unsigned short* dst = (h < 16) ? qb : kb;
    const int dstride = (h < 16) ? 1024 : 256;
    const int dcol = (h < 16) ? col_wave : (col_wave - 1024);
    const bool ev = (lrow & 1) == 0;
#pragma unroll
    for (int mi = 0; mi < 4; ++mi) {
#pragma unroll
      for (int ni = 0; ni < 2; ++ni) {
        int ff = (hc + ni * 16 + lrow) >> 1;
#pragma unroll
        for (int r = 0; r < 4; ++r) {
          int s = sb + mi * 16 + quad * 4 + r;
          float v = acc[mi][ni][r];
          float p = __shfl_xor(v, 1);
          float c = cs[s * 32 + ff];
          float si = sn[s * 32 + ff];
          float o = ev ? (v * c - p * si) : (v * c + p * si);
          size_t row = row0 + wy * 64 + mi * 16 + quad * 4 + r;
          dst[row * dstride + dcol + ni * 16 + lrow] = f2bf(o);
        }
      }
    }
  } else {
    const int kvh = h - 20;
    const int g = bidx * KVH + kvh;
#pragma unroll
    for (int mi = 0; mi < 4; ++mi) {
#pragma unroll
      for (int ni = 0; ni < 2; ++ni) {
        int d = hc + ni * 16 + lrow;
        int s0 = sb + mi * 16 + quad * 4;
        ushort4 o;
        o.x = f2bf(acc[mi][ni][0]); o.y = f2bf(acc[mi][ni][1]);
        o.z = f2bf(acc[mi][ni][2]); o.w = f2bf(acc[mi][ni][3]);
        *(ushort4*)&vt[((size_t)(g * 64 + d)) * S + s0] = o;
      }
    }
  }
}

// ---------------------------------------------------------------------------
// Output projection: out[4096,1024] fp32 = ao[4096,1024] bf16 * wo[1024,1024].
// A staged as direct bf16 uint4 copy (swizzled write); B micro-transposed.
// ---------------------------------------------------------------------------
__global__ __launch_bounds__(256) void gemm_bt_kernel(
    const unsigned short* __restrict__ ao, const float* __restrict__ wo,
    float* __restrict__ out) {
  __shared__ unsigned short As[2 * 128 * 32];
  __shared__ unsigned short Bs[2 * 64 * 32];
  const int tid = threadIdx.x;
  const int lane = tid & 63, wvid = tid >> 6;
  const int wy = wvid >> 1, wx = wvid & 1;
  const int quad = lane >> 4, lrow = lane & 15;
  const size_t row0 = (size_t)blockIdx.x * 128;
  const size_t col0 = (size_t)blockIdx.y * 64;

  floatx4 acc[4][2];
#pragma unroll
  for (int i = 0; i < 4; ++i)
#pragma unroll
    for (int j = 0; j < 2; ++j) acc[i][j] = floatx4{0.f, 0.f, 0.f, 0.f};

  const int ar = tid >> 2;
  const int ac = tid & 3;
  const int aswz = ((ac ^ ((ar >> 2) & 3)) * 8);
  const int aoffL = ar * 32 + aswz;
  const int aoffH = (ar + 64) * 32 + aswz;
  const unsigned short* gAL = ao + (row0 + ar) * 1024 + ac * 8;
  const unsigned short* gAH = ao + (row0 + 64 + ar) * 1024 + ac * 8;

  const int bsec = tid >> 7;
  const int bu = tid & 127;
  const int bn = (bu & 15) * 4;
  const int bkq = (bu >> 4) * 4;
  const int bchunk = bkq >> 3, bslot = (bkq >> 2) & 1;
  const float* gw = wo + (size_t)(bsec * 32 + bkq) * 1024 + col0 + bn;

  const int fswz = (quad ^ (lrow >> 2)) * 8;

  for (int k0 = 0; k0 < 1024; k0 += 64) {
    uint4 u0l = *(const uint4*)(gAL + k0);
    uint4 u0h = *(const uint4*)(gAH + k0);
    uint4 u1l = *(const uint4*)(gAL + k0 + 32);
    uint4 u1h = *(const uint4*)(gAH + k0 + 32);
    const float* gwk = gw + (size_t)k0 * 1024;
    float4 b0 = *(const float4*)(gwk);
    float4 b1 = *(const float4*)(gwk + 1024);
    float4 b2 = *(const float4*)(gwk + 2048);
    float4 b3 = *(const float4*)(gwk + 3072);

    __syncthreads();
    *(uint4*)&As[aoffL]        = u0l;
    *(uint4*)&As[aoffH]        = u0h;
    *(uint4*)&As[4096 + aoffL] = u1l;
    *(uint4*)&As[4096 + aoffH] = u1h;
#pragma unroll
    for (int dn = 0; dn < 4; ++dn) {
      const float* c0 = (const float*)&b0;
      const float* c1 = (const float*)&b1;
      const float* c2 = (const float*)&b2;
      const float* c3 = (const float*)&b3;
      int n = bn + dn;
      int key = (n >> 2) & 3;
      uint2 o;
      o.x = (unsigned)f2bf(c0[dn]) | ((unsigned)f2bf(c1[dn]) << 16);
      o.y = (unsigned)f2bf(c2[dn]) | ((unsigned)f2bf(c3[dn]) << 16);
      *(uint2*)&Bs[bsec * 2048 + n * 32 + ((bchunk ^ key) * 8) + bslot * 4] = o;
    }
    __syncthreads();

#pragma unroll
    for (int s = 0; s < 2; ++s) {
      short8 af[4], bg[2];
#pragma unroll
      for (int mi = 0; mi < 4; ++mi)
        af[mi] = *(const short8*)&As[s * 4096 + (wy * 64 + mi * 16 + lrow) * 32 + fswz];
#pragma unroll
      for (int ni = 0; ni < 2; ++ni)
        bg[ni] = *(const short8*)&Bs[s * 2048 + (wx * 32 + ni * 16 + lrow) * 32 + fswz];
#pragma unroll
      for (int mi = 0; mi < 4; ++mi)
#pragma unroll
        for (int ni = 0; ni < 2; ++ni)
          acc[mi][ni] = __builtin_amdgcn_mfma_f32_16x16x32_bf16(af[mi], bg[ni], acc[mi][ni], 0, 0, 0);
    }
  }

#pragma unroll
  for (int mi = 0; mi < 4; ++mi)
#pragma unroll
    for (int ni = 0; ni < 2; ++ni) {
      size_t col = col0 + wx * 32 + ni * 16 + lrow;
      size_t rowb = row0 + wy * 64 + mi * 16 + quad * 4;
#pragma unroll
      for (int r = 0; r < 4; ++r)
        out[(rowb + r) * 1024 + col] = acc[mi][ni][r];
    }
}

// ---------------------------------------------------------------------------
// MFMA flash attention. One wave per (b, h, 16-query block). (unchanged)
// ---------------------------------------------------------------------------
__global__ __launch_bounds__(256) void attn_kernel(
    const unsigned short* __restrict__ qb,   // [BS][1024]
    const unsigned short* __restrict__ kb,   // [BS][256]
    const unsigned short* __restrict__ vt,   // [B*KVH][64][S]
    unsigned short* __restrict__ ao) {       // [BS][1024]
  __shared__ __align__(16) unsigned short plds[4][16][104];
  const int w = threadIdx.x >> 6, lane = threadIdx.x & 63;
  const int lrow = lane & 15, quad = lane >> 4;
  const int wg = blockIdx.x * 4 + w;
  const int h = wg & (H - 1);
  const int qblk = wg >> 4;
  const int i0 = (qblk & (S / 16 - 1)) * 16;
  const int b = qblk >> 7;
  const int kvh = h >> 2;
  const int jbase = i0 - 80;

  const unsigned short* qrow = qb + (size_t)(b * S + i0 + lrow) * 1024 + h * 64 + quad * 8;
  short8 qf0 = *(const short8*)qrow;
  short8 qf1 = *(const short8*)(qrow + 32);

  floatx4 sc[6];
#pragma unroll
  for (int t = 0; t < 6; ++t) {
    int j = jbase + t * 16 + lrow;
    int jc = j < 0 ? 0 : j;
    const unsigned short* krow = kb + (size_t)(b * S + jc) * 256 + kvh * 64 + quad * 8;
    short8 kf0 = *(const short8*)krow;
    short8 kf1 = *(const short8*)(krow + 32);
    floatx4 a = {0.f, 0.f, 0.f, 0.f};
    a = __builtin_amdgcn_mfma_f32_16x16x32_bf16(qf0, kf0, a, 0, 0, 0);
    a = __builtin_amdgcn_mfma_f32_16x16x32_bf16(qf1, kf1, a, 0, 0, 0);
    sc[t] = a;
  }

  float sv[6][4];
  float mx[4] = {-1e30f, -1e30f, -1e30f, -1e30f};
#pragma unroll
  for (int t = 0; t < 6; ++t) {
    int j = jbase + t * 16 + lrow;
#pragma unroll
    for (int r = 0; r < 4; ++r) {
      int dji = (i0 + quad * 4 + r) - j;
      bool valid = (j >= 0) && (dji >= 0) && (dji <= 64);
      float s = valid ? sc[t][r] * 0.125f : -1e30f;
      sv[t][r] = s;
      mx[r] = fmaxf(mx[r], s);
    }
  }
#pragma unroll
  for (int r = 0; r < 4; ++r)
#pragma unroll
    for (int off = 8; off > 0; off >>= 1)
      mx[r] = fmaxf(mx[r], __shfl_xor(mx[r], off));

  float ls[4] = {0.f, 0.f, 0.f, 0.f};
#pragma unroll
  for (int t = 0; t < 6; ++t)
#pragma unroll
    for (int r = 0; r < 4; ++r) {
      float e = __expf(sv[t][r] - mx[r]);
      sv[t][r] = e;
      ls[r] += e;
    }
#pragma unroll
  for (int r = 0; r < 4; ++r) {
#pragma unroll
    for (int off = 8; off > 0; off >>= 1)
      ls[r] += __shfl_xor(ls[r], off);
    ls[r] = 1.f / ls[r];
  }
#pragma unroll
  for (int t = 0; t < 6; ++t)
#pragma unroll
    for (int r = 0; r < 4; ++r)
      plds[w][quad * 4 + r][t * 16 + lrow] = f2bf(sv[t][r] * ls[r]);
  __syncthreads();

  floatx4 oc[4];
#pragma unroll
  for (int mt = 0; mt < 4; ++mt) oc[mt] = floatx4{0.f, 0.f, 0.f, 0.f};
  const unsigned short* vbase = vt + (size_t)(b * KVH + kvh) * 64 * S;
#pragma unroll
  for (int c = 0; c < 3; ++c) {
    short8 pf = *(const short8*)&plds[w][lrow][c * 32 + quad * 8];
    int j = jbase + c * 32 + quad * 8;
    int jc = j < 0 ? 0 : j;
#pragma unroll
    for (int mt = 0; mt < 4; ++mt) {
      short8 vf = *(const short8*)(vbase + (size_t)(mt * 16 + lrow) * S + jc);
      oc[mt] = __builtin_amdgcn_mfma_f32_16x16x32_bf16(vf, pf, oc[mt], 0, 0, 0);
    }
  }

#pragma unroll
  for (int mt = 0; mt < 4; ++mt) {
    ushort4 o;
    o.x = f2bf(oc[mt][0]); o.y = f2bf(oc[mt][1]);
    o.z = f2bf(oc[mt][2]); o.w = f2bf(oc[mt][3]);
    *(ushort4*)(ao + (size_t)(b * S + i0 + lrow) * 1024 + h * 64 + mt * 16 + quad * 4) = o;
  }
}

// ---------------------------------------------------------------------------
extern "C" void kernel_launch(void* const* d_in, const int* in_sizes, int n_in,
                              void* d_out, int out_size, void* d_ws, size_t ws_size,
                              hipStream_t stream) {
  const float* x  = (const float*)d_in[0];
  const float* fc = (const float*)d_in[1];
  const float* fs = (const float*)d_in[2];
  const float* wq = (const float*)d_in[3];
  const float* wk = (const float*)d_in[4];
  const float* wv = (const float*)d_in[5];
  const float* wo = (const float*)d_in[6];
  float* out = (float*)d_out;

  // ws: [qb 8M][kb 2M][vT 2M][ao 8M] = 20 MiB
  char* base = (char*)d_ws;
  unsigned short* qb = (unsigned short*)base;
  unsigned short* kb = (unsigned short*)(base + (8u << 20));
  unsigned short* vT = (unsigned short*)(base + (10u << 20));
  unsigned short* ao = (unsigned short*)(base + (12u << 20));

  // 1) fused QKV GEMM (raw fp32 inputs) + RoPE + V-transpose
  gemm_qkv_kernel<<<dim3(BS / 128, QS / 64), 256, 0, stream>>>(
      x, wq, wk, wv, fc, fs, qb, kb, vT);

  // 2) MFMA attention -> ao bf16 [4096,1024]
  attn_kernel<<<(BS / 16) * H / 4, 256, 0, stream>>>(qb, kb, vT, ao);

  // 3) output projection (raw fp32 wo) -> fp32
  gemm_bt_kernel<<<dim3(BS / 128, D / 64), 256, 0, stream>>>(ao, wo, out);
}

// Round 12
// 133.511 us; speedup vs baseline: 1.3452x; 1.2394x over previous
//
#include <hip/hip_runtime.h>
#include <hip/hip_bf16.h>

constexpr int B = 2, S = 2048, D = 1024;
constexpr int H = 16, KVH = 4, HD = 64;
constexpr int BS = B * S;                 // 4096
constexpr int QS = 1536;                  // fused qkv width

typedef __attribute__((ext_vector_type(8))) short short8;
typedef __attribute__((ext_vector_type(4))) float floatx4;

#define GPTR(p) ((__attribute__((address_space(1))) void*)(p))
#define LPTR(p) ((__attribute__((address_space(3))) void*)(p))

static __device__ __forceinline__ unsigned short f2bf(float f) {
  union { float f; unsigned u; } c{f};
  unsigned r = (c.u + 0x7FFFu + ((c.u >> 16) & 1u)) >> 16;
  return (unsigned short)r;
}

// ---------------------------------------------------------------------------
// Prep: x fp32 -> bf16 (blocks [0,4096)) and all 4 weight transposes
// (blocks [4096, 4096+2560)). fp32 [K=1024,N] -> bf16 [N,1024].
// ---------------------------------------------------------------------------
__global__ __launch_bounds__(256) void prep_kernel(
    const float* __restrict__ x,
    const float* __restrict__ wq, const float* __restrict__ wk,
    const float* __restrict__ wv, const float* __restrict__ wo,
    unsigned short* __restrict__ xb,
    unsigned short* __restrict__ wqkvT, unsigned short* __restrict__ woT) {
  int bz = blockIdx.x;
  if (bz < 4096) {
    int t = bz * 256 + threadIdx.x;
    float4 v = ((const float4*)x)[t];
    ushort4 o;
    o.x = f2bf(v.x); o.y = f2bf(v.y); o.z = f2bf(v.z); o.w = f2bf(v.w);
    ((ushort4*)xb)[t] = o;
    return;
  }
  __shared__ float t[32][33];
  int z = bz - 4096;                 // 0..2559
  int zx = z % 80, zy = z / 80;      // region-select, k-block
  const float* src; unsigned short* dst; int N, dstOff, nb;
  if (zx < 32)      { src = wq; dst = wqkvT; N = 1024; dstOff = 0;    nb = zx; }
  else if (zx < 40) { src = wk; dst = wqkvT; N = 256;  dstOff = 1024; nb = zx - 32; }
  else if (zx < 48) { src = wv; dst = wqkvT; N = 256;  dstOff = 1280; nb = zx - 40; }
  else              { src = wo; dst = woT;   N = 1024; dstOff = 0;    nb = zx - 48; }
  int n0 = nb * 32, k0 = zy * 32;
  int tx = threadIdx.x & 31, ty = threadIdx.x >> 5;
#pragma unroll
  for (int r = 0; r < 4; ++r)
    t[ty + r * 8][tx] = src[(size_t)(k0 + ty + r * 8) * N + n0 + tx];
  __syncthreads();
#pragma unroll
  for (int r = 0; r < 4; ++r)
    dst[(size_t)(dstOff + n0 + ty + r * 8) * D + k0 + tx] = f2bf(t[tx][ty + r * 8]);
}

// ---------------------------------------------------------------------------
// Shared GEMM K-loop (R9-proven): 128x64 tile, BK=128 (four 32-k sections,
// m97 linear [row][32] LDS layout), async global_load_lds staging.
// Grid: blockIdx.x = ROW tile (fast -> XCD partition of A), .y = COL tile.
// ---------------------------------------------------------------------------
#define GEMM_PROLOGUE(Aptr, Btptr)                                            \
  __shared__ unsigned short As[4 * 128 * 32];                                 \
  __shared__ unsigned short Bs[4 * 64 * 32];                                  \
  const int tid = threadIdx.x;                                                \
  const int lane = tid & 63, wvid = tid >> 6;                                 \
  const int wy = wvid >> 1, wx = wvid & 1;                                    \
  const int quad = lane >> 4, lrow = lane & 15;                               \
  const size_t row0 = (size_t)blockIdx.x * 128;                               \
  const size_t col0 = (size_t)blockIdx.y * 64;                                \
  floatx4 acc[4][2];                                                          \
  _Pragma("unroll") for (int i = 0; i < 4; ++i)                               \
    _Pragma("unroll") for (int j = 0; j < 2; ++j)                             \
      acc[i][j] = floatx4{0.f, 0.f, 0.f, 0.f};                                \
  const int arow = wvid * 32 + (lane >> 2);                                   \
  const int brow = wvid * 16 + (lane >> 2);                                   \
  const int schk = (lane & 3) * 8;                                            \
  const unsigned short* gA = (Aptr) + (row0 + arow) * 1024 + schk;            \
  const unsigned short* gB = (Btptr) + (col0 + brow) * 1024 + schk;           \
  char* ldsA = (char*)As + wvid * 2048;                                       \
  char* ldsB = (char*)Bs + wvid * 1024;                                       \
  for (int k0 = 0; k0 < 1024; k0 += 128) {                                    \
    __syncthreads();                                                          \
    _Pragma("unroll") for (int hf = 0; hf < 4; ++hf) {                        \
      __builtin_amdgcn_global_load_lds(GPTR(gA + k0 + hf * 32),               \
                                       LPTR(ldsA + hf * 8192), 16, 0, 0);     \
      __builtin_amdgcn_global_load_lds(GPTR(gA + 16 * 1024 + k0 + hf * 32),   \
                                       LPTR(ldsA + hf * 8192 + 1024), 16, 0, 0); \
      __builtin_amdgcn_global_load_lds(GPTR(gB + k0 + hf * 32),               \
                                       LPTR(ldsB + hf * 4096), 16, 0, 0);     \
    }                                                                         \
    __syncthreads();                                                          \
    _Pragma("unroll") for (int hf = 0; hf < 4; ++hf) {                        \
      short8 af[4], bg[2];                                                    \
      _Pragma("unroll") for (int mi = 0; mi < 4; ++mi)                        \
        af[mi] = *(const short8*)&As[hf * 4096 +                              \
                                     (wy * 64 + mi * 16 + lrow) * 32 + quad * 8]; \
      _Pragma("unroll") for (int ni = 0; ni < 2; ++ni)                        \
        bg[ni] = *(const short8*)&Bs[hf * 2048 +                              \
                                     (wx * 32 + ni * 16 + lrow) * 32 + quad * 8]; \
      _Pragma("unroll") for (int mi = 0; mi < 4; ++mi)                        \
        _Pragma("unroll") for (int ni = 0; ni < 2; ++ni)                      \
          acc[mi][ni] = __builtin_amdgcn_mfma_f32_16x16x32_bf16(              \
              af[mi], bg[ni], acc[mi][ni], 0, 0, 0);                          \
    }                                                                         \
  }

// ---------------------------------------------------------------------------
// Fused QKV GEMM + RoPE + V-transpose.  C[4096,1536] never materialized.
// ---------------------------------------------------------------------------
__global__ __launch_bounds__(256) void gemm_qkv_kernel(
    const unsigned short* __restrict__ A, const unsigned short* __restrict__ Bt,
    const float* __restrict__ cs, const float* __restrict__ sn,
    unsigned short* __restrict__ qb, unsigned short* __restrict__ kb,
    unsigned short* __restrict__ vt) {
  GEMM_PROLOGUE(A, Bt)

  const int col_wave = (int)col0 + wx * 32;     // wave-uniform, within one head
  const int h = col_wave >> 6;
  const int hc = col_wave & 63;
  const int sb = (int)(row0 & 2047) + wy * 64;
  const int bidx = (int)(row0 >> 11);

  if (h < 20) {
    unsigned short* dst = (h < 16) ? qb : kb;
    const int dstride = (h < 16) ? 1024 : 256;
    const int dcol = (h < 16) ? col_wave : (col_wave - 1024);
    const bool ev = (lrow & 1) == 0;
#pragma unroll
    for (int mi = 0; mi < 4; ++mi) {
#pragma unroll
      for (int ni = 0; ni < 2; ++ni) {
        int ff = (hc + ni * 16 + lrow) >> 1;
#pragma unroll
        for (int r = 0; r < 4; ++r) {
          int s = sb + mi * 16 + quad * 4 + r;
          float v = acc[mi][ni][r];
          float p = __shfl_xor(v, 1);
          float c = cs[s * 32 + ff];
          float si = sn[s * 32 + ff];
          float o = ev ? (v * c - p * si) : (v * c + p * si);
          size_t row = row0 + wy * 64 + mi * 16 + quad * 4 + r;
          dst[row * dstride + dcol + ni * 16 + lrow] = f2bf(o);
        }
      }
    }
  } else {
    const int kvh = h - 20;
    const int g = bidx * KVH + kvh;
#pragma unroll
    for (int mi = 0; mi < 4; ++mi) {
#pragma unroll
      for (int ni = 0; ni < 2; ++ni) {
        int d = hc + ni * 16 + lrow;
        int s0 = sb + mi * 16 + quad * 4;
        ushort4 o;
        o.x = f2bf(acc[mi][ni][0]); o.y = f2bf(acc[mi][ni][1]);
        o.z = f2bf(acc[mi][ni][2]); o.w = f2bf(acc[mi][ni][3]);
        *(ushort4*)&vt[((size_t)(g * 64 + d)) * S + s0] = o;
      }
    }
  }
}

// ---------------------------------------------------------------------------
// Output projection GEMM -> fp32 C. Same structure.
// ---------------------------------------------------------------------------
__global__ __launch_bounds__(256) void gemm_bt_kernel(
    const unsigned short* __restrict__ A, const unsigned short* __restrict__ Bt,
    float* __restrict__ C, int N) {
  GEMM_PROLOGUE(A, Bt)

#pragma unroll
  for (int mi = 0; mi < 4; ++mi)
#pragma unroll
    for (int ni = 0; ni < 2; ++ni) {
      size_t col = col0 + wx * 32 + ni * 16 + lrow;
      size_t rowb = row0 + wy * 64 + mi * 16 + quad * 4;
#pragma unroll
      for (int r = 0; r < 4; ++r)
        C[(rowb + r) * N + col] = acc[mi][ni][r];
    }
}

// ---------------------------------------------------------------------------
// MFMA flash attention, block-cooperative K/V LDS staging.
// Block = 4 waves sharing (b, qblk, kvh); wave w handles head 4*kvh + w.
// K tile [96][72] (rows j = jbase..jbase+95, 2-way banking, b128-aligned),
// V^T tile [64][104]. j<0 rows/chunks clamped to 0 (masked or P=0).
// LDS total 40.4 KB -> 4 blocks/CU at grid 1024.
// ---------------------------------------------------------------------------
__global__ __launch_bounds__(256) void attn_kernel(
    const unsigned short* __restrict__ qb,   // [BS][1024]
    const unsigned short* __restrict__ kb,   // [BS][256]
    const unsigned short* __restrict__ vt,   // [B*KVH][64][S]
    unsigned short* __restrict__ ao) {       // [BS][1024]
  __shared__ __align__(16) unsigned short Ks[96 * 72];     // 13824 B
  __shared__ __align__(16) unsigned short Vs[64 * 104];    // 13312 B
  __shared__ __align__(16) unsigned short plds[4][16][104];// 13312 B
  const int tid = threadIdx.x;
  const int w = tid >> 6, lane = tid & 63;
  const int lrow = lane & 15, quad = lane >> 4;
  const int kvh = blockIdx.x & 3;           // shared across the 4 waves
  const int qblk = blockIdx.x >> 2;
  const int h = kvh * 4 + w;
  const int i0 = (qblk & (S / 16 - 1)) * 16;
  const int b = qblk >> 7;
  const int jbase = i0 - 80;
  const int bS = b * S;

  // ---- cooperative staging: K (96 chunks x 8) and V^T (64 x 12 chunks) ----
#pragma unroll
  for (int it = 0; it < 3; ++it) {
    int c = tid + it * 256;                 // 0..767
    int rr = c >> 3, oo = (c & 7) * 8;      // K: row rr (j = jbase+rr), cols oo..+7
    int j = jbase + rr;
    j = j < 0 ? 0 : j;                      // garbage masked later
    *(uint4*)&Ks[rr * 72 + oo] =
        *(const uint4*)&kb[(size_t)(bS + j) * 256 + kvh * 64 + oo];
  }
  const unsigned short* vbase = vt + (size_t)(b * KVH + kvh) * 64 * S;
#pragma unroll
  for (int it = 0; it < 3; ++it) {
    int c = tid + it * 256;                 // 0..767
    int rr = c / 12, oo = c % 12;           // V: d-row rr, j-chunk oo (8-aligned)
    int j = jbase + oo * 8;
    j = j < 0 ? 0 : j;                      // whole chunk <0 or >=0 (jbase%16==0)
    *(uint4*)&Vs[rr * 104 + oo * 8] = *(const uint4*)&vbase[(size_t)rr * S + j];
  }
  __syncthreads();

  // ---- QK^T (K frags from LDS) ----
  const unsigned short* qrow = qb + (size_t)(bS + i0 + lrow) * 1024 + h * 64 + quad * 8;
  short8 qf0 = *(const short8*)qrow;
  short8 qf1 = *(const short8*)(qrow + 32);

  floatx4 sc[6];
#pragma unroll
  for (int t = 0; t < 6; ++t) {
    int kr = t * 16 + lrow;
    short8 kf0 = *(const short8*)&Ks[kr * 72 + quad * 8];
    short8 kf1 = *(const short8*)&Ks[kr * 72 + 32 + quad * 8];
    floatx4 a = {0.f, 0.f, 0.f, 0.f};
    a = __builtin_amdgcn_mfma_f32_16x16x32_bf16(qf0, kf0, a, 0, 0, 0);
    a = __builtin_amdgcn_mfma_f32_16x16x32_bf16(qf1, kf1, a, 0, 0, 0);
    sc[t] = a;
  }

  // ---- mask + softmax (C-layout: col j = jbase+t*16+lrow, row i0+quad*4+r) ----
  float sv[6][4];
  float mx[4] = {-1e30f, -1e30f, -1e30f, -1e30f};
#pragma unroll
  for (int t = 0; t < 6; ++t) {
    int j = jbase + t * 16 + lrow;
#pragma unroll
    for (int r = 0; r < 4; ++r) {
      int dji = (i0 + quad * 4 + r) - j;
      bool valid = (j >= 0) && (dji >= 0) && (dji <= 64);
      float s = valid ? sc[t][r] * 0.125f : -1e30f;
      sv[t][r] = s;
      mx[r] = fmaxf(mx[r], s);
    }
  }
#pragma unroll
  for (int r = 0; r < 4; ++r)
#pragma unroll
    for (int off = 8; off > 0; off >>= 1)
      mx[r] = fmaxf(mx[r], __shfl_xor(mx[r], off));

  float ls[4] = {0.f, 0.f, 0.f, 0.f};
#pragma unroll
  for (int t = 0; t < 6; ++t)
#pragma unroll
    for (int r = 0; r < 4; ++r) {
      float e = __expf(sv[t][r] - mx[r]);
      sv[t][r] = e;
      ls[r] += e;
    }
#pragma unroll
  for (int r = 0; r < 4; ++r) {
#pragma unroll
    for (int off = 8; off > 0; off >>= 1)
      ls[r] += __shfl_xor(ls[r], off);
    ls[r] = 1.f / ls[r];
  }
#pragma unroll
  for (int t = 0; t < 6; ++t)
#pragma unroll
    for (int r = 0; r < 4; ++r)
      plds[w][quad * 4 + r][t * 16 + lrow] = f2bf(sv[t][r] * ls[r]);
  __syncthreads();

  // ---- PV: D[m=d][n=q] = sum_j Vs[d][j] * P[q][j] ----
  floatx4 oc[4];
#pragma unroll
  for (int mt = 0; mt < 4; ++mt) oc[mt] = floatx4{0.f, 0.f, 0.f, 0.f};
#pragma unroll
  for (int c = 0; c < 3; ++c) {
    short8 pf = *(const short8*)&plds[w][lrow][c * 32 + quad * 8];
#pragma unroll
    for (int mt = 0; mt < 4; ++mt) {
      short8 vf = *(const short8*)&Vs[(mt * 16 + lrow) * 104 + c * 32 + quad * 8];
      oc[mt] = __builtin_amdgcn_mfma_f32_16x16x32_bf16(vf, pf, oc[mt], 0, 0, 0);
    }
  }

#pragma unroll
  for (int mt = 0; mt < 4; ++mt) {
    ushort4 o;
    o.x = f2bf(oc[mt][0]); o.y = f2bf(oc[mt][1]);
    o.z = f2bf(oc[mt][2]); o.w = f2bf(oc[mt][3]);
    *(ushort4*)(ao + (size_t)(bS + i0 + lrow) * 1024 + h * 64 + mt * 16 + quad * 4) = o;
  }
}

// ---------------------------------------------------------------------------
extern "C" void kernel_launch(void* const* d_in, const int* in_sizes, int n_in,
                              void* d_out, int out_size, void* d_ws, size_t ws_size,
                              hipStream_t stream) {
  const float* x  = (const float*)d_in[0];
  const float* fc = (const float*)d_in[1];
  const float* fs = (const float*)d_in[2];
  const float* wq = (const float*)d_in[3];
  const float* wk = (const float*)d_in[4];
  const float* wv = (const float*)d_in[5];
  const float* wo = (const float*)d_in[6];
  float* out = (float*)d_out;

  // ws: [xb 8M][wqkvT 3M][woT 2M][qb 8M][kb 2M][vT 2M][ao 8M] = 33 MiB
  char* base = (char*)d_ws;
  unsigned short* xb    = (unsigned short*)base;
  unsigned short* wqkvT = (unsigned short*)(base + (8u << 20));
  unsigned short* woT   = (unsigned short*)(base + (11u << 20));
  unsigned short* qb    = (unsigned short*)(base + (13u << 20));
  unsigned short* kb    = (unsigned short*)(base + (21u << 20));
  unsigned short* vT    = (unsigned short*)(base + (23u << 20));
  unsigned short* ao    = (unsigned short*)(base + (25u << 20));

  // 1) prep: cast x + transpose all weights
  prep_kernel<<<4096 + 2560, 256, 0, stream>>>(x, wq, wk, wv, wo, xb, wqkvT, woT);

  // 2) fused QKV GEMM + RoPE + V-transpose (grid = rows x cols, XCD-aware)
  gemm_qkv_kernel<<<dim3(BS / 128, QS / 64), 256, 0, stream>>>(
      xb, wqkvT, fc, fs, qb, kb, vT);

  // 3) MFMA attention (block-cooperative K/V staging) -> ao bf16
  attn_kernel<<<(BS / 16) * H / 4, 256, 0, stream>>>(qb, kb, vT, ao);

  // 4) output projection -> fp32 (grid = rows x cols, XCD-aware)
  gemm_bt_kernel<<<dim3(BS / 128, D / 64), 256, 0, stream>>>(ao, woT, out, D);
}